// Round 10
// baseline (103.202 us; speedup 1.0000x reference)
//
#include <hip/hip_runtime.h>

// GNN layer (fp32 in/out):
//   out_i = (e_i@W1^T + b1 + b2) + dinv_i * sum_{j in N(i)} z_j
//   z_j   = dinv_j * (e_j@W1^T + e_j^2@W2^T)
// (refactor of: (e + L e)@W1^T + b1 + (L e^2)@W2^T + b2, L = D^-1/2 A D^-1/2)
// Pipeline: two-level LDS counting sort -> exact CSR, MFMA transform,
// gather-sum. Symmetric edge layout row=[u;it], col=[it;u] -> 1M pair pass.
// HW rules learned on this problem:
//  (r4) sub-dword global stores -> ECC RMW amplification. Pack to >=4B.
//  (r5) scattered 4B stores write ~64B/line (cross-XCD migration).
//  (r6) scattered global atomics: same writeback physics.
//  (r7) scattered RETURNING atomics: ~32B/op write-through to HBM.
//  (r8) dense [n,64]@[64,64] on VALU is LDS-issue-bound -> MFMA (G10).
//  (r9) k_main gather serves 256MB at ~6.1 TB/s effective = structural floor;
//       z-row is already minimal (64 x bf16 = 128B).
// r10: rec packed to 1 dword ((v<<8)|(u&255), n<2^18) + k4 LDS record cache.

#define NB 256          // blocks for count/scatter passes (must equal blockDim)
#define MAXBUCK 608     // LDS arrays sized for nbuck = ceil(n/256) = 564
#define RECCAP 8192     // k4 LDS record cache (max bucket ~5.3K records)

typedef short bf16x8 __attribute__((ext_vector_type(8)));
typedef float f32x4 __attribute__((ext_vector_type(4)));

__device__ __forceinline__ float bf2f(unsigned short u) {
    union { unsigned int i; float f; } c; c.i = ((unsigned int)u) << 16; return c.f;
}
__device__ __forceinline__ unsigned int f2bf(float f) {
    union { float f; unsigned int i; } c; c.f = f;
    unsigned int r = c.i + 0x7FFFu + ((c.i >> 16) & 1u);  // RTN-even
    return r >> 16;
}
__device__ __forceinline__ unsigned int pk2(float a, float b) {
    return f2bf(a) | (f2bf(b) << 16);
}

// ---------------- CSR build: two-level LDS counting sort ----------------

__global__ __launch_bounds__(256) void k1_count(const int* __restrict__ row,
                                                const int* __restrict__ col,
                                                int* __restrict__ H, int Eh, int nbuck) {
    __shared__ int hist[MAXBUCK];
    int tid = threadIdx.x, b = blockIdx.x;
    for (int i = tid; i < nbuck; i += 256) hist[i] = 0;
    __syncthreads();
    int chunk = (Eh + NB - 1) / NB;
    int e0 = b * chunk, e1 = min(e0 + chunk, Eh);
    for (int e = e0 + tid; e < e1; e += 256) {
        int u = row[e], v = col[e];
        atomicAdd(&hist[u >> 8], 1);
        atomicAdd(&hist[v >> 8], 1);
    }
    __syncthreads();
    for (int i = tid; i < nbuck; i += 256) H[b * nbuck + i] = hist[i];
}

__global__ __launch_bounds__(256) void k2_colscan(const int* __restrict__ H,
                                                  int* __restrict__ Off,
                                                  int* __restrict__ btot, int nbuck) {
    __shared__ int lds[256];
    int t = threadIdx.x, beta = blockIdx.x;
    int v = H[t * nbuck + beta];
    lds[t] = v;
    __syncthreads();
    for (int off = 1; off < 256; off <<= 1) {
        int x = (t >= off) ? lds[t - off] : 0;
        __syncthreads();
        lds[t] += x;
        __syncthreads();
    }
    Off[beta * NB + t] = lds[t] - v;
    if (t == 255) btot[beta] = lds[255];
}

__global__ __launch_bounds__(1024) void k2b_bscan(const int* __restrict__ btot,
                                                  int* __restrict__ bbase, int nbuck,
                                                  int E, int* __restrict__ start, int n) {
    __shared__ int lds[1024];
    int t = threadIdx.x;
    int v = (t < nbuck) ? btot[t] : 0;
    lds[t] = v;
    __syncthreads();
    for (int off = 1; off < 1024; off <<= 1) {
        int x = (t >= off) ? lds[t - off] : 0;
        __syncthreads();
        lds[t] += x;
        __syncthreads();
    }
    if (t < nbuck) bbase[t] = lds[t] - v;
    if (t == nbuck) bbase[t] = E;
    if (t == 0) start[n] = E;
}

// rec packing: (v<<8) | (u&255); bucket of u implicit from region.
__global__ __launch_bounds__(256) void k3_scatter(const int* __restrict__ row,
                                                  const int* __restrict__ col,
                                                  const int* __restrict__ Off,
                                                  const int* __restrict__ bbase,
                                                  unsigned int* __restrict__ rec,
                                                  int Eh, int nbuck) {
    __shared__ int cur[MAXBUCK];
    int tid = threadIdx.x, b = blockIdx.x;
    for (int i = tid; i < nbuck; i += 256) cur[i] = bbase[i] + Off[i * NB + b];
    __syncthreads();
    int chunk = (Eh + NB - 1) / NB;
    int e0 = b * chunk, e1 = min(e0 + chunk, Eh);
    for (int e = e0 + tid; e < e1; e += 256) {
        int u = row[e], v = col[e];
        int p = atomicAdd(&cur[u >> 8], 1);
        rec[p] = ((unsigned int)v << 8) | (u & 255);
        int q = atomicAdd(&cur[v >> 8], 1);
        rec[q] = ((unsigned int)u << 8) | (v & 255);
    }
}

__global__ __launch_bounds__(256) void k4_local(const unsigned int* __restrict__ rec,
                                                const int* __restrict__ bbase,
                                                int* __restrict__ start,
                                                float* __restrict__ dinv,
                                                int* __restrict__ scol, int n) {
    __shared__ int hist[256], lcur[256], lds[256];
    __shared__ unsigned int cache[RECCAP];
    int t = threadIdx.x, beta = blockIdx.x;
    int base = bbase[beta];
    int cnt = bbase[beta + 1] - base;
    bool cached = cnt <= RECCAP;
    hist[t] = 0;
    __syncthreads();
    for (int r = t; r < cnt; r += 256) {
        unsigned int rr = rec[base + r];
        if (cached) cache[r] = rr;
        atomicAdd(&hist[rr & 255], 1);
    }
    __syncthreads();
    int h = hist[t];
    lds[t] = h;
    __syncthreads();
    for (int off = 1; off < 256; off <<= 1) {
        int x = (t >= off) ? lds[t - off] : 0;
        __syncthreads();
        lds[t] += x;
        __syncthreads();
    }
    int excl = lds[t] - h;
    int node = (beta << 8) + t;
    if (node < n) {
        start[node] = base + excl;
        dinv[node] = h > 0 ? rsqrtf((float)h) : 0.0f;
    }
    lcur[t] = base + excl;
    __syncthreads();
    for (int r = t; r < cnt; r += 256) {
        unsigned int rr = cached ? cache[r] : rec[base + r];
        int p = atomicAdd(&lcur[rr & 255], 1);
        scol[p] = (int)(rr >> 8);
    }
}

// ---------------- MFMA transform ----------------
// 4 waves x 16-node tiles; mfma_f32_16x16x32_bf16, K=64 -> 2 frags.
// LDS bf16 tiles XOR-swizzled (dw ^= (row&7)<<2) -> <=2-way conflicts.
// Epilogue packs dword q = dims (q, q+32).
__global__ __launch_bounds__(256) void k_xform(
    const float4* __restrict__ embed4, const float* __restrict__ dinv,
    const float4* __restrict__ W1_4, const float4* __restrict__ W2_4,
    const float* __restrict__ b1, const float* __restrict__ b2,
    unsigned int* __restrict__ y1p, unsigned int* __restrict__ zp, int n) {
    __shared__ __align__(16) unsigned int lW[2][2048];     // [mat][row*32+dw] 64x64 bf16
    __shared__ __align__(16) unsigned int lA[4][2][512];   // [wave][e|e2][row*32+dw] 16x64

    int tid = threadIdx.x;
    int wave = tid >> 6, lane = tid & 63;
    int L = lane & 15, hi = lane >> 4;

#pragma unroll
    for (int p = 0; p < 8; p++) {
        int idx = p * 256 + tid;              // 0..2047
        int mat = idx >> 10, rem = idx & 1023;
        int row = rem >> 4, col4 = rem & 15;
        float4 v = (mat ? W2_4 : W1_4)[rem];
        int dw = (row * 32 + col4 * 2) ^ ((row & 7) << 2);
        *(int2*)&lW[mat][dw] = make_int2(pk2(v.x, v.y), pk2(v.z, v.w));
    }
    __syncthreads();

    bf16x8 bfr[2][4][2];
#pragma unroll
    for (int m = 0; m < 2; m++)
#pragma unroll
        for (int t = 0; t < 4; t++)
#pragma unroll
            for (int kf = 0; kf < 2; kf++) {
                int row = 16 * t + L;
                int dw = (row * 32 + kf * 16 + hi * 4) ^ ((L & 7) << 2);
                int4 raw = *(const int4*)&lW[m][dw];
                bfr[m][t][kf] = *(bf16x8*)&raw;
            }

    int tb16 = blockIdx.x * 64 + wave * 16;
#pragma unroll
    for (int p = 0; p < 4; p++) {
        int idx = p * 64 + lane;              // 0..255
        int row = idx >> 4, col4 = idx & 15;
        int node = tb16 + row;
        int nc = node < n ? node : n - 1;
        float4 v = embed4[(size_t)nc * 16 + col4];
        int dw = (row * 32 + col4 * 2) ^ ((row & 7) << 2);
        *(int2*)&lA[wave][0][dw] = make_int2(pk2(v.x, v.y), pk2(v.z, v.w));
        *(int2*)&lA[wave][1][dw] = make_int2(pk2(v.x * v.x, v.y * v.y),
                                             pk2(v.z * v.z, v.w * v.w));
    }
    // wave-local LDS write->read: compiler-inserted lgkmcnt orders it.

    f32x4 accY[4], accS[4];
#pragma unroll
    for (int t = 0; t < 4; t++) { accY[t] = (f32x4)0.f; accS[t] = (f32x4)0.f; }
#pragma unroll
    for (int kf = 0; kf < 2; kf++) {
        int dw = (L * 32 + kf * 16 + hi * 4) ^ ((L & 7) << 2);
        int4 rawE = *(const int4*)&lA[wave][0][dw];
        int4 rawQ = *(const int4*)&lA[wave][1][dw];
        bf16x8 aE = *(bf16x8*)&rawE;
        bf16x8 aQ = *(bf16x8*)&rawQ;
#pragma unroll
        for (int t = 0; t < 4; t++) {
            accY[t] = __builtin_amdgcn_mfma_f32_16x16x32_bf16(aE, bfr[0][t][kf], accY[t], 0, 0, 0);
            accS[t] = __builtin_amdgcn_mfma_f32_16x16x32_bf16(aQ, bfr[1][t][kf], accS[t], 0, 0, 0);
        }
    }

    float bs0 = b1[L] + b2[L];
    float bs1 = b1[16 + L] + b2[16 + L];
    float bs2 = b1[32 + L] + b2[32 + L];
    float bs3 = b1[48 + L] + b2[48 + L];
#pragma unroll
    for (int r = 0; r < 4; r++) {
        int node = tb16 + 4 * hi + r;
        if (node >= n) continue;
        float di = dinv[node];
        float y0 = accY[0][r], y1 = accY[1][r], y2 = accY[2][r], y3 = accY[3][r];
        float s0 = accS[0][r], s1 = accS[1][r], s2 = accS[2][r], s3 = accS[3][r];
        size_t base = (size_t)node * 32;
        y1p[base + L]      = pk2(y0 + bs0, y2 + bs2);
        y1p[base + 16 + L] = pk2(y1 + bs1, y3 + bs3);
        zp[base + L]       = pk2(di * (y0 + s0), di * (y2 + s2));
        zp[base + 16 + L]  = pk2(di * (y1 + s1), di * (y3 + s3));
    }
}

// ---------------- gather-sum ----------------
__global__ __launch_bounds__(256, 8) void k_main(
    const ushort4* __restrict__ zb4, const ushort4* __restrict__ y1b4,
    const int* __restrict__ start, const int* __restrict__ scol,
    const float* __restrict__ dinv, float2* __restrict__ out2, int n) {
    int tid = threadIdx.x;
    int wave = tid >> 6, lane = tid & 63, g = lane >> 4, l = lane & 15;
    int i = blockIdx.x * 16 + wave * 4 + g;
    bool valid = i < n;
    int ii = valid ? i : 0;
    int s0 = start[ii];
    int s1 = valid ? start[ii + 1] : s0;

    float4 acc = make_float4(0.f, 0.f, 0.f, 0.f);
    for (int e = s0; e < s1; e += 16) {
        int cnt = s1 - e;
        cnt = cnt > 16 ? 16 : cnt;
        int jv = scol[e + (l < cnt ? l : 0)];
#pragma unroll 8
        for (int k = 0; k < 16; k++) {
            int j = __shfl(jv, (g << 4) + k, 64);
            float m = (k < cnt) ? 1.0f : 0.0f;
            ushort4 z = zb4[(size_t)j * 16 + l];
            acc.x = fmaf(bf2f(z.x), m, acc.x);
            acc.y = fmaf(bf2f(z.y), m, acc.y);
            acc.z = fmaf(bf2f(z.z), m, acc.z);
            acc.w = fmaf(bf2f(z.w), m, acc.w);
        }
    }
    if (valid) {
        float di = dinv[i];
        ushort4 yb = y1b4[(size_t)i * 16 + l];
        float4 o;
        o.x = fmaf(di, acc.x, bf2f(yb.x));   // dim 2l
        o.y = fmaf(di, acc.y, bf2f(yb.y));   // dim 2l+32
        o.z = fmaf(di, acc.z, bf2f(yb.z));   // dim 2l+1
        o.w = fmaf(di, acc.w, bf2f(yb.w));   // dim 2l+33
        out2[(size_t)i * 32 + l] = make_float2(o.x, o.z);
        out2[(size_t)i * 32 + 16 + l] = make_float2(o.y, o.w);
    }
}

extern "C" void kernel_launch(void* const* d_in, const int* in_sizes, int n_in,
                              void* d_out, int out_size, void* d_ws, size_t ws_size,
                              hipStream_t stream) {
    const float* embed = (const float*)d_in[0];
    const int* row = (const int*)d_in[1];
    const int* col = (const int*)d_in[2];
    const float* W1 = (const float*)d_in[3];
    const float* b1 = (const float*)d_in[4];
    const float* W2 = (const float*)d_in[5];
    const float* b2 = (const float*)d_in[6];
    float* out = (float*)d_out;

    int n = in_sizes[0] / 64;   // 144242
    int E = in_sizes[1];        // 2,000,000
    int Eh = E / 2;             // symmetric pairs: row=[u;it], col=[it;u]
    int nbuck = (n + 255) >> 8; // 564
    size_t n64 = (size_t)n * 64;
    if (nbuck > MAXBUCK) return;  // fixed-size LDS guard
    if (n >= (1 << 18)) return;   // rec packing guard (v<<8 must fit 32b)

    char* ws = (char*)d_ws;
    size_t off = 0;
    unsigned int* zp = (unsigned int*)(ws + off);  off += n64 * 2;        // 18.5 MB
    unsigned int* y1p = (unsigned int*)(ws + off); off += n64 * 2;        // 18.5 MB
    unsigned int* rec = (unsigned int*)(ws + off); off += (size_t)E * 4;  // 8 MB
    int* scol = (int*)(ws + off);                  off += (size_t)E * 4;  // 8 MB
    int* H = (int*)(ws + off);                     off += (size_t)NB * nbuck * 4;
    int* Off = (int*)(ws + off);                   off += (size_t)nbuck * NB * 4;
    int* btot = (int*)(ws + off);                  off += (size_t)nbuck * 4;
    int* bbase = (int*)(ws + off);                 off += (size_t)(nbuck + 1) * 4;
    int* start = (int*)(ws + off);                 off += (size_t)(n + 1) * 4;
    float* dinv = (float*)(ws + off);              off += (size_t)n * 4;

    if (off > ws_size) return;  // ws too small -> out stays zero (0.707 absmax signal)

    k1_count<<<NB, 256, 0, stream>>>(row, col, H, Eh, nbuck);
    k2_colscan<<<nbuck, 256, 0, stream>>>(H, Off, btot, nbuck);
    k2b_bscan<<<1, 1024, 0, stream>>>(btot, bbase, nbuck, E, start, n);
    k3_scatter<<<NB, 256, 0, stream>>>(row, col, Off, bbase, rec, Eh, nbuck);
    k4_local<<<nbuck, 256, 0, stream>>>(rec, bbase, start, dinv, scol, n);
    k_xform<<<(n + 63) / 64, 256, 0, stream>>>((const float4*)embed, dinv,
                                               (const float4*)W1, (const float4*)W2,
                                               b1, b2, y1p, zp, n);
    k_main<<<(n + 15) / 16, 256, 0, stream>>>((const ushort4*)zp, (const ushort4*)y1p,
                                              start, scol, dinv, (float2*)out, n);
}